// Round 1
// baseline (221.363 us; speedup 1.0000x reference)
//
#include <hip/hip_runtime.h>

// JointHistLayer: out[b,k,j] = (1/N) sum_n phi(x[b,n]-mu_k) * phi(y[b,n]-mu_j)
// B=8, K=256, N=65536.  phi(d) = sigmoid((d+L/2)/W) - sigmoid((d-L/2)/W),
// L=1/256, W=L/2.5.  With t = 640x - 2.5k - 1.25 and e = exp(-t):
//   phi = CD*e / (1 + CS*e + e^2),  CD = e^1.25-e^-1.25, CS = e^1.25+e^-1.25
// e recurrence across consecutive bins: e_{k+1} = e_k * e^2.5.

#define NPIX    65536
#define NSLICES 16
#define SLICE   (NPIX / NSLICES)   // 4096 pixels per slice
#define BK      64                 // pixels per LDS chunk
#define LDA     72                 // 64 + 8 halfs pad (keeps b128 reads <=4-way)
#define TILE    128

typedef _Float16 half8  __attribute__((ext_vector_type(8)));
typedef _Float16 half2t __attribute__((ext_vector_type(2)));
typedef float    f32x4  __attribute__((ext_vector_type(4)));

#define CA (-923.3248261893424f)    // -640*log2(e)
#define CK (3.6067376022224087f)    // 2.5*log2(e)
#define CB (1.8033688011112043f)    // 1.25*log2(e)
#define CS (3.7768477543199803f)    // e^1.25 + e^-1.25
#define CD (3.2038381605996003f)    // e^1.25 - e^-1.25
#define ESTEP (12.182493960703473f) // e^2.5

__device__ __forceinline__ float fast_exp2(float a) {
#if __has_builtin(__builtin_amdgcn_exp2f)
  return __builtin_amdgcn_exp2f(a);
#else
  return exp2f(a);
#endif
}

__device__ __forceinline__ float fast_rcp(float a) {
#if __has_builtin(__builtin_amdgcn_rcpf)
  return __builtin_amdgcn_rcpf(a);
#else
  return 1.0f / a;
#endif
}

__device__ __forceinline__ float phi_from_e(float e) {
  float den = fmaf(e, e + CS, 1.0f);   // 1 + CS*e + e^2
  return (CD * e) * fast_rcp(den);
}

__global__ __launch_bounds__(256, 2)
void jh_main(const float* __restrict__ x, const float* __restrict__ y,
             float* __restrict__ partial, float* __restrict__ out,
             int use_atomic)
{
  __shared__ _Float16 phx[TILE * LDA];  // Phi_x[binRow][pixel], 18432 B
  __shared__ _Float16 phy[TILE * LDA];

  const int bid  = blockIdx.x;
  const int s    = bid & (NSLICES - 1);   // n-slice
  const int tile = (bid >> 4) & 3;        // which 128x128 quadrant of C
  const int b    = bid >> 6;              // batch
  const int k0   = (tile >> 1) * TILE;
  const int j0   = (tile & 1) * TILE;

  const int t    = threadIdx.x;
  const int g    = t >> 5;            // 0..7: row group (16 rows each)
  const int p    = (t & 31) * 2;      // pixel pair within chunk
  const int w    = t >> 6;            // wave 0..3
  const int lane = t & 63;
  const int mrow = lane & 15;
  const int quad = lane >> 4;
  const int wrow = (w >> 1) * 64;     // wave's 64x64 quadrant of the 128x128 tile
  const int wcol = (w & 1) * 64;

  const float* xb = x + b * NPIX;
  const float* yb = y + b * NPIX;

  // per-thread constants: exp2 arg at strip row 0 (bin k0+16g / j0+16g)
  const float cxk = fmaf((float)(k0 + 16 * g), CK, CB);
  const float cyk = fmaf((float)(j0 + 16 * g), CK, CB);

  f32x4 acc[4][4];
#pragma unroll
  for (int r = 0; r < 4; ++r)
#pragma unroll
    for (int c = 0; c < 4; ++c)
      acc[r][c] = (f32x4){0.f, 0.f, 0.f, 0.f};

  _Float16* wpx = &phx[(16 * g) * LDA + p];
  _Float16* wpy = &phy[(16 * g) * LDA + p];
  const _Float16* ax = &phx[(wrow + mrow) * LDA + quad * 8];
  const _Float16* by = &phy[(wcol + mrow) * LDA + quad * 8];

  const float* xptr = xb + s * SLICE + p;
  const float* yptr = yb + s * SLICE + p;
  const int NC = SLICE / BK;

  float2 xv = *(const float2*)(xptr);
  float2 yv = *(const float2*)(yptr);

  for (int c = 0; c < NC; ++c) {
    // start of e-recurrence for this chunk's 2 x-pixels / 2 y-pixels
    float ex0 = fast_exp2(fminf(fmaf(xv.x, CA, cxk), 60.0f));
    float ex1 = fast_exp2(fminf(fmaf(xv.y, CA, cxk), 60.0f));
    float ey0 = fast_exp2(fminf(fmaf(yv.x, CA, cyk), 60.0f));
    float ey1 = fast_exp2(fminf(fmaf(yv.y, CA, cyk), 60.0f));

    // prefetch next chunk's pixels (latency hidden behind phi loop)
    const int cn = (c + 1 < NC) ? c + 1 : c;
    float2 xvn = *(const float2*)(xptr + cn * BK);
    float2 yvn = *(const float2*)(yptr + cn * BK);

#pragma unroll
    for (int i = 0; i < 16; ++i) {
      auto hx = __builtin_amdgcn_cvt_pkrtz(phi_from_e(ex0), phi_from_e(ex1));
      auto hy = __builtin_amdgcn_cvt_pkrtz(phi_from_e(ey0), phi_from_e(ey1));
      *(decltype(hx)*)(wpx + i * LDA) = hx;
      *(decltype(hy)*)(wpy + i * LDA) = hy;
      ex0 *= ESTEP; ex1 *= ESTEP; ey0 *= ESTEP; ey1 *= ESTEP;
    }
    __syncthreads();

#pragma unroll
    for (int kk = 0; kk < BK; kk += 32) {
      half8 af[4], bf[4];
#pragma unroll
      for (int r = 0; r < 4; ++r) af[r] = *(const half8*)(ax + (r * 16) * LDA + kk);
#pragma unroll
      for (int r = 0; r < 4; ++r) bf[r] = *(const half8*)(by + (r * 16) * LDA + kk);
#pragma unroll
      for (int r = 0; r < 4; ++r)
#pragma unroll
        for (int cc = 0; cc < 4; ++cc)
          acc[r][cc] = __builtin_amdgcn_mfma_f32_16x16x32_f16(af[r], bf[cc], acc[r][cc], 0, 0, 0);
    }
    __syncthreads();

    xv = xvn; yv = yvn;
  }

  // epilogue: C/D layout col = lane&15, row = quad*4 + reg
  const float scale = 1.0f / (float)NPIX;
  if (!use_atomic) {
    float* pb = partial + (((size_t)(b * 4 + tile) * NSLICES + s) << 14);
#pragma unroll
    for (int r = 0; r < 4; ++r)
#pragma unroll
      for (int cc = 0; cc < 4; ++cc) {
        const int row = wrow + r * 16 + quad * 4;
        const int col = wcol + cc * 16 + mrow;
#pragma unroll
        for (int q = 0; q < 4; ++q)
          pb[(row + q) * TILE + col] = acc[r][cc][q] * scale;
      }
  } else {
    float* ob = out + ((size_t)b << 16);
#pragma unroll
    for (int r = 0; r < 4; ++r)
#pragma unroll
      for (int cc = 0; cc < 4; ++cc) {
        const int row = k0 + wrow + r * 16 + quad * 4;
        const int col = j0 + wcol + cc * 16 + mrow;
#pragma unroll
        for (int q = 0; q < 4; ++q)
          atomicAdd(&ob[(row + q) * 256 + col], acc[r][cc][q] * scale);
      }
  }
}

__global__ __launch_bounds__(256)
void jh_reduce(const float* __restrict__ ws, float* __restrict__ out)
{
  const int idx = blockIdx.x * 256 + threadIdx.x;  // flat (b,k,j)
  const int b = idx >> 16;
  const int k = (idx >> 8) & 255;
  const int j = idx & 255;
  const int tile = ((k >> 7) << 1) | (j >> 7);
  const int i = ((k & 127) << 7) | (j & 127);
  const float* p = ws + (((size_t)(b * 4 + tile) * NSLICES) << 14) + i;
  float sum = 0.f;
#pragma unroll
  for (int s = 0; s < NSLICES; ++s) sum += p[(size_t)s << 14];
  out[idx] = sum;
}

extern "C" void kernel_launch(void* const* d_in, const int* in_sizes, int n_in,
                              void* d_out, int out_size, void* d_ws, size_t ws_size,
                              hipStream_t stream)
{
  const float* x = (const float*)d_in[0];
  const float* y = (const float*)d_in[1];
  float* out = (float*)d_out;

  const size_t need = (size_t)8 * 4 * NSLICES * TILE * TILE * sizeof(float); // 33.5 MB
  if (ws_size >= need) {
    float* ws = (float*)d_ws;
    jh_main<<<512, 256, 0, stream>>>(x, y, ws, out, 0);
    jh_reduce<<<2048, 256, 0, stream>>>(ws, out);
  } else {
    hipMemsetAsync(d_out, 0, (size_t)out_size * sizeof(float), stream);
    jh_main<<<512, 256, 0, stream>>>(x, y, nullptr, out, 1);
  }
}

// Round 2
// 181.514 us; speedup vs baseline: 1.2195x; 1.2195x over previous
//
#include <hip/hip_runtime.h>

// JointHistLayer: out[b,k,j] = (1/N) sum_n phi(x[b,n]-mu_k) * phi(y[b,n]-mu_j)
// B=8, K=256, N=65536.  phi_k(x) = sigmoid(v_k) - sigmoid(v_{k+1}),
// v_i = 640x - 2.5i  (telescoping boundaries: one new sigmoid per bin).
// f_i = e^{-v_i}, f_{i+1} = f_i * e^{2.5}; sigma = rcp(1+f).
// f -> inf => sigma -> 0, f -> 0 => sigma -> 1; phi stays finite, no NaN.

#define NPIX 65536
#define TILE 128
#define BK   64      // pixels per LDS chunk
#define LDA  72      // 64 + 8 halfs pad

typedef _Float16 half8 __attribute__((ext_vector_type(8)));
typedef float    f32x4 __attribute__((ext_vector_type(4)));

#define CA    (-923.3248261893424f)   // -640*log2(e)
#define CK    (3.6067376022224087f)   // 2.5*log2(e)
#define ESTEP (12.182493960703473f)   // e^2.5

__device__ __forceinline__ float fast_exp2(float a) {
#if __has_builtin(__builtin_amdgcn_exp2f)
  return __builtin_amdgcn_exp2f(a);
#else
  return exp2f(a);
#endif
}
__device__ __forceinline__ float fast_rcp(float a) {
#if __has_builtin(__builtin_amdgcn_rcpf)
  return __builtin_amdgcn_rcpf(a);
#else
  return 1.0f / a;
#endif
}

template <int NS>
__global__ __launch_bounds__(256, 4)
void jh_main(const float* __restrict__ x, const float* __restrict__ y,
             float* __restrict__ partial, float* __restrict__ out,
             int use_atomic)
{
  constexpr int SLICE = NPIX / NS;

  __shared__ _Float16 phx[TILE * LDA];  // 18432 B
  __shared__ _Float16 phy[TILE * LDA];

  const int bid  = blockIdx.x;
  const int s    = bid & (NS - 1);
  const int tile = (bid / NS) & 3;
  const int b    = bid / (4 * NS);
  const int k0   = (tile >> 1) * TILE;
  const int j0   = (tile & 1) * TILE;

  const int t    = threadIdx.x;
  const int g    = t >> 5;            // 0..7: 16-row strip
  const int p    = (t & 31) * 2;      // pixel pair within chunk
  const int w    = t >> 6;            // wave 0..3
  const int lane = t & 63;
  const int mrow = lane & 15;
  const int quad = lane >> 4;
  const int wrow = (w >> 1) * 64;
  const int wcol = (w & 1) * 64;

  // exp2 args at the strip's first bin boundary
  const float ckx = (float)(k0 + 16 * g) * CK;
  const float cky = (float)(j0 + 16 * g) * CK;

  f32x4 acc[4][4];
#pragma unroll
  for (int r = 0; r < 4; ++r)
#pragma unroll
    for (int c = 0; c < 4; ++c)
      acc[r][c] = (f32x4){0.f, 0.f, 0.f, 0.f};

  _Float16* wpx = &phx[(16 * g) * LDA + p];
  _Float16* wpy = &phy[(16 * g) * LDA + p];
  const _Float16* ax = &phx[(wrow + mrow) * LDA + quad * 8];
  const _Float16* by = &phy[(wcol + mrow) * LDA + quad * 8];

  const float* xptr = x + b * NPIX + s * SLICE + p;
  const float* yptr = y + b * NPIX + s * SLICE + p;
  const int NC = SLICE / BK;

  float2 xv = *(const float2*)(xptr);
  float2 yv = *(const float2*)(yptr);

  for (int c = 0; c < NC; ++c) {
    // boundary sigmoids at strip row 0
    float fx0 = fast_exp2(fmaf(xv.x, CA, ckx));
    float fx1 = fast_exp2(fmaf(xv.y, CA, ckx));
    float fy0 = fast_exp2(fmaf(yv.x, CA, cky));
    float fy1 = fast_exp2(fmaf(yv.y, CA, cky));
    float sx0 = fast_rcp(1.0f + fx0);
    float sx1 = fast_rcp(1.0f + fx1);
    float sy0 = fast_rcp(1.0f + fy0);
    float sy1 = fast_rcp(1.0f + fy1);

    // prefetch next chunk's pixels
    const int cn = (c + 1 < NC) ? c + 1 : c;
    float2 xvn = *(const float2*)(xptr + cn * BK);
    float2 yvn = *(const float2*)(yptr + cn * BK);

#pragma unroll
    for (int i = 0; i < 16; ++i) {
      fx0 *= ESTEP; fx1 *= ESTEP; fy0 *= ESTEP; fy1 *= ESTEP;
      float nx0 = fast_rcp(1.0f + fx0);
      float nx1 = fast_rcp(1.0f + fx1);
      float ny0 = fast_rcp(1.0f + fy0);
      float ny1 = fast_rcp(1.0f + fy1);
      auto hx = __builtin_amdgcn_cvt_pkrtz(sx0 - nx0, sx1 - nx1);
      auto hy = __builtin_amdgcn_cvt_pkrtz(sy0 - ny0, sy1 - ny1);
      *(decltype(hx)*)(wpx + i * LDA) = hx;
      *(decltype(hy)*)(wpy + i * LDA) = hy;
      sx0 = nx0; sx1 = nx1; sy0 = ny0; sy1 = ny1;
    }
    __syncthreads();

#pragma unroll
    for (int kk = 0; kk < BK; kk += 32) {
      half8 af[4], bf[4];
#pragma unroll
      for (int r = 0; r < 4; ++r) af[r] = *(const half8*)(ax + (r * 16) * LDA + kk);
#pragma unroll
      for (int r = 0; r < 4; ++r) bf[r] = *(const half8*)(by + (r * 16) * LDA + kk);
#pragma unroll
      for (int r = 0; r < 4; ++r)
#pragma unroll
        for (int cc = 0; cc < 4; ++cc)
          acc[r][cc] = __builtin_amdgcn_mfma_f32_16x16x32_f16(af[r], bf[cc], acc[r][cc], 0, 0, 0);
    }
    __syncthreads();

    xv = xvn; yv = yvn;
  }

  // epilogue: C/D layout col = lane&15, row = quad*4 + reg
  const float scale = 1.0f / (float)NPIX;
  if (!use_atomic) {
    float* pb = partial + (((size_t)((b * 4 + tile) * NS + s)) << 14);
#pragma unroll
    for (int r = 0; r < 4; ++r)
#pragma unroll
      for (int cc = 0; cc < 4; ++cc) {
        const int row = wrow + r * 16 + quad * 4;
        const int col = wcol + cc * 16 + mrow;
#pragma unroll
        for (int q = 0; q < 4; ++q)
          pb[(row + q) * TILE + col] = acc[r][cc][q] * scale;
      }
  } else {
    float* ob = out + ((size_t)b << 16);
#pragma unroll
    for (int r = 0; r < 4; ++r)
#pragma unroll
      for (int cc = 0; cc < 4; ++cc) {
        const int row = k0 + wrow + r * 16 + quad * 4;
        const int col = j0 + wcol + cc * 16 + mrow;
#pragma unroll
        for (int q = 0; q < 4; ++q)
          atomicAdd(&ob[(row + q) * 256 + col], acc[r][cc][q] * scale);
      }
  }
}

__global__ __launch_bounds__(256)
void jh_reduce(const float* __restrict__ ws, float* __restrict__ out, int NS)
{
  const int idx = blockIdx.x * 256 + threadIdx.x;  // flat (b,k,j)
  const int b = idx >> 16;
  const int k = (idx >> 8) & 255;
  const int j = idx & 255;
  const int tile = ((k >> 7) << 1) | (j >> 7);
  const int i = ((k & 127) << 7) | (j & 127);
  const float* p = ws + (((size_t)((b * 4 + tile) * NS)) << 14) + i;
  float sum = 0.f;
#pragma unroll 8
  for (int s = 0; s < NS; ++s) sum += p[(size_t)s << 14];
  out[idx] = sum;
}

extern "C" void kernel_launch(void* const* d_in, const int* in_sizes, int n_in,
                              void* d_out, int out_size, void* d_ws, size_t ws_size,
                              hipStream_t stream)
{
  const float* x = (const float*)d_in[0];
  const float* y = (const float*)d_in[1];
  float* out = (float*)d_out;

  const size_t need32 = (size_t)8 * 4 * 32 * TILE * TILE * sizeof(float); // 67.1 MB
  const size_t need16 = need32 / 2;                                      // 33.5 MB
  if (ws_size >= need32) {
    float* ws = (float*)d_ws;
    jh_main<32><<<1024, 256, 0, stream>>>(x, y, ws, out, 0);
    jh_reduce<<<2048, 256, 0, stream>>>(ws, out, 32);
  } else if (ws_size >= need16) {
    float* ws = (float*)d_ws;
    jh_main<16><<<512, 256, 0, stream>>>(x, y, ws, out, 0);
    jh_reduce<<<2048, 256, 0, stream>>>(ws, out, 16);
  } else {
    hipMemsetAsync(d_out, 0, (size_t)out_size * sizeof(float), stream);
    jh_main<16><<<512, 256, 0, stream>>>(x, y, nullptr, out, 1);
  }
}